// Round 3
// baseline (298.600 us; speedup 1.0000x reference)
//
#include <hip/hip_runtime.h>

#define N_PIX  131072       // 32*64*64 pixels
#define D      64
#define K      512
#define Q_OFF  0            // out[0 .. 8388607]   quantized_ste (NCHW)
#define L_OFF  8388608      // out[8388608]        commitment loss
#define I_OFF  8388609      // out[8388609 .. ]    indices (as float)

#define CHUNK  32           // codes per LDS chunk (8 KB)
#define NCHUNK (K / CHUNK)  // 16

// ws layout (floats)
#define WS_ET     0                 // 512*64 transposed embeddings
#define WS_ENORM  (K * D)           // 512 code norms
#define WS_PART   (K * D + K)       // 512 partial loss sums

__global__ __launch_bounds__(256) void vq_prep(const float* __restrict__ E,
                                               float* __restrict__ ws) {
    int k = blockIdx.x * 256 + threadIdx.x;   // 0..511
    float* ET = ws + WS_ET;
    float nsq = 0.f;
#pragma unroll 8
    for (int d = 0; d < D; ++d) {
        float v = E[d * K + k];               // coalesced across k
        ET[k * D + d] = v;
        nsq = fmaf(v, v, nsq);
    }
    ws[WS_ENORM + k] = nsq;
}

// async global->LDS, 16 B per lane, linear layout (dest = wave base + lane*16)
__device__ __forceinline__ void gload_lds16(const float* g, float* l) {
    __builtin_amdgcn_global_load_lds(
        (const __attribute__((address_space(1))) unsigned int*)g,
        (__attribute__((address_space(3))) unsigned int*)l, 16, 0, 0);
}

__global__ __launch_bounds__(256) void vq_main(const float* __restrict__ x,
                                               const float* __restrict__ ws,
                                               float* __restrict__ out,
                                               float* __restrict__ partial) {
    const float* ET    = ws + WS_ET;
    const float* enorm = ws + WS_ENORM;

    __shared__ float lds[2][CHUNK * D];       // 2 x 8 KB

    const int tid  = threadIdx.x;
    const int wave = tid >> 6;
    const int lane = tid & 63;

    int n  = blockIdx.x * 256 + tid;          // pixel id
    int b  = n >> 12;                         // n / 4096
    int hw = n & 4095;

    const float* xp = x + ((size_t)b << 18) + hw;   // b*64*4096 + hw
    float xv[D];
#pragma unroll
    for (int d = 0; d < D; ++d) xv[d] = xp[(size_t)d << 12];

    // stage chunk 0 into buffer 0: 2048 floats, 256 threads x 2 x 16B
    {
        const int off0 = wave * 256 + lane * 4;
        gload_lds16(ET + off0,        &lds[0][off0]);
        gload_lds16(ET + off0 + 1024, &lds[0][off0 + 1024]);
    }
    __syncthreads();                           // drains vmcnt -> chunk 0 ready

    float best  = 3.4e38f;
    int   bestk = 0;

    for (int c = 0; c < NCHUNK; ++c) {
        // issue prefetch of chunk c+1 into the other buffer
        if (c + 1 < NCHUNK) {
            const int off0 = wave * 256 + lane * 4;
            const float* src = ET + (c + 1) * (CHUNK * D) + off0;
            float* dst = &lds[(c + 1) & 1][off0];
            gload_lds16(src,        dst);
            gload_lds16(src + 1024, dst + 1024);
        }

        const float* eb = lds[c & 1];
        const int kbase = c * CHUNK;
#pragma unroll 4
        for (int kk = 0; kk < CHUNK; ++kk) {
            const float4* ek = reinterpret_cast<const float4*>(eb + (kk << 6)); // uniform -> broadcast
            float a0 = 0.f, a1 = 0.f, a2 = 0.f, a3 = 0.f;
#pragma unroll
            for (int q = 0; q < 16; ++q) {
                float4 e = ek[q];
                a0 = fmaf(xv[4*q+0], e.x, a0);
                a1 = fmaf(xv[4*q+1], e.y, a1);
                a2 = fmaf(xv[4*q+2], e.z, a2);
                a3 = fmaf(xv[4*q+3], e.w, a3);
            }
            float dot  = (a0 + a1) + (a2 + a3);
            float dist = fmaf(-2.f, dot, enorm[kbase + kk]); // ||x||^2 const per pixel
            if (dist < best) { best = dist; bestk = kbase + kk; }  // strict < = first min
        }

        if (c + 1 < NCHUNK) __syncthreads();   // stage done + all waves done with old buffer
    }

    out[I_OFF + n] = (float)bestk;

    const float* qv = ET + (bestk << 6);
    float* op = out + Q_OFF + ((size_t)b << 18) + hw;
    float lsum = 0.f;
#pragma unroll
    for (int d = 0; d < D; ++d) {
        float qd = qv[d];
        op[(size_t)d << 12] = qd;                 // coalesced across w
        float diff = xv[d] - qd;
        lsum = fmaf(diff, diff, lsum);
    }

    // deterministic block reduction of the loss
#pragma unroll
    for (int off = 32; off > 0; off >>= 1)
        lsum += __shfl_down(lsum, off, 64);
    __shared__ float wsum[4];
    if ((tid & 63) == 0) wsum[tid >> 6] = lsum;
    __syncthreads();
    if (tid == 0)
        partial[blockIdx.x] = (wsum[0] + wsum[1]) + (wsum[2] + wsum[3]);
}

__global__ __launch_bounds__(256) void vq_final(const float* __restrict__ partial,
                                                float* __restrict__ out) {
    int t = threadIdx.x;
    float s = partial[t] + partial[t + 256];
#pragma unroll
    for (int off = 32; off > 0; off >>= 1)
        s += __shfl_down(s, off, 64);
    __shared__ float wsum[4];
    if ((t & 63) == 0) wsum[t >> 6] = s;
    __syncthreads();
    if (t == 0)
        out[L_OFF] = ((wsum[0] + wsum[1]) + (wsum[2] + wsum[3])) * (1.f / 8388608.f);
}

extern "C" void kernel_launch(void* const* d_in, const int* in_sizes, int n_in,
                              void* d_out, int out_size, void* d_ws, size_t ws_size,
                              hipStream_t stream) {
    const float* x = (const float*)d_in[0];
    const float* E = (const float*)d_in[1];
    float* out = (float*)d_out;
    float* ws  = (float*)d_ws;

    hipLaunchKernelGGL(vq_prep,  dim3(2),   dim3(256), 0, stream, E, ws);
    hipLaunchKernelGGL(vq_main,  dim3(512), dim3(256), 0, stream, x, ws, out, ws + WS_PART);
    hipLaunchKernelGGL(vq_final, dim3(1),   dim3(256), 0, stream, ws + WS_PART, out);
}

// Round 5
// 75.203 us; speedup vs baseline: 3.9706x; 3.9706x over previous
//
#include <hip/hip_runtime.h>

#define D      64
#define K      512
#define Q_OFF  0            // out[0 .. 8388607]   quantized_ste (NCHW)
#define L_OFF  8388608      // out[8388608]        commitment loss
#define I_OFF  8388609      // out[8388609 .. ]    indices (131072)

// ws layout (floats)
#define WS_ET    0          // 512*64 transposed embeddings (fp32, exact)
#define WS_EN    32768      // 512 ||e||^2
#define WS_ENH   33280      // 512 0.5*||e||^2
#define WS_PART  33792      // 512 partial loss sums

// B-fragment tables staged in out[] (quantized region, rewritten later):
// hi at short8[0..4095], lo at short8[4096..8191]  (64 KB each)
#define B_LO_OFF 4096

typedef __attribute__((ext_vector_type(8))) short short8;   // 8 bf16 = 4 VGPRs
typedef __attribute__((ext_vector_type(4))) float f32x4;

static __device__ __forceinline__ unsigned short f2bf(float f) {
    unsigned u = __float_as_uint(f);
    u += 0x7fffu + ((u >> 16) & 1u);       // RTN-even
    return (unsigned short)(u >> 16);
}
static __device__ __forceinline__ float bf2f(unsigned short h) {
    return __uint_as_float(((unsigned)h) << 16);
}

// ---------------------------------------------------------------- prep ----
// Packs B-operand fragments of (-e) in hi/lo bf16 into the (temporarily
// unused) quantized region of `out`: layout [tile t:32][kstep s:2][lane:64]
// of short8; slot j holds (-E)[k = s*32 + (lane>>4)*8 + j][code = t*16+(lane&15)].
// Also builds ET (fp32 transpose) + ||e||^2 tables in ws.
__global__ __launch_bounds__(256) void vq_prep(const float* __restrict__ E,
                                               float* __restrict__ ws,
                                               float* __restrict__ out) {
    int g = blockIdx.x * 256 + threadIdx.x;   // 0..2047 = (t, lane)
    int t = g >> 6, lane = g & 63;
    int col = lane & 15, kg = lane >> 4;
    int code = t * 16 + col;
    short8* bhp = (short8*)out;               // 64 KB
    short8* blp = (short8*)out + B_LO_OFF;    // next 64 KB
#pragma unroll
    for (int s = 0; s < 2; ++s) {
        short8 h, l;
#pragma unroll
        for (int j = 0; j < 8; ++j) {
            int k = s * 32 + kg * 8 + j;
            float v = -E[k * K + code];
            unsigned short hb = f2bf(v);
            h[j] = (short)hb;
            l[j] = (short)f2bf(v - bf2f(hb));
        }
        bhp[(t * 2 + s) * 64 + lane] = h;
        blp[(t * 2 + s) * 64 + lane] = l;
    }
    if (g < K) {
        float nsq = 0.f;
#pragma unroll 8
        for (int d = 0; d < D; ++d) {
            float v = E[d * K + g];
            ws[WS_ET + g * D + d] = v;
            nsq = fmaf(v, v, nsq);
        }
        ws[WS_EN + g]  = nsq;
        ws[WS_ENH + g] = 0.5f * nsq;
    }
}

// ---------------------------------------------------------------- dist ----
// Block = 256 thr = 4 waves; wave owns 64 pixels (4 M-tiles of 16) x all 512
// codes (32 N-tiles of 16).  acc init = 0.5*||e||^2, A = x (hi+lo bf16),
// B = -e (hi+lo)  =>  acc = 0.5*||e||^2 - x.e  (same argmin as distance).
// Tracks top-2 (value, index) per pixel, cross-lane merges, writes packed
// (i1 | i2<<16) into out's index slots for the recheck kernel.
__global__ __launch_bounds__(256, 2) void vq_dist(const float* __restrict__ x,
                                                  const float* __restrict__ ws,
                                                  float* __restrict__ out) {
    const int tid = threadIdx.x, w = tid >> 6, lane = tid & 63;
    const int col = lane & 15, rowg = lane >> 4;
    const int pixw = blockIdx.x * 256 + w * 64;

    // ---- load x fragments and split to bf16 hi/lo: A[mt][s]
    short8 ah[4][2], al[4][2];
#pragma unroll
    for (int mt = 0; mt < 4; ++mt) {
        int pix = pixw + mt * 16 + col;
        const float* xp = x + ((size_t)(pix >> 12) << 18) + (pix & 4095);
#pragma unroll
        for (int s = 0; s < 2; ++s) {
            short8 h, l;
#pragma unroll
            for (int j = 0; j < 8; ++j) {
                float v = xp[(size_t)(s * 32 + rowg * 8 + j) << 12];
                unsigned short hb = f2bf(v);
                h[j] = (short)hb;
                l[j] = (short)f2bf(v - bf2f(hb));
            }
            ah[mt][s] = h; al[mt][s] = l;
        }
    }

    const short8* bhp = (const short8*)out;
    const short8* blp = (const short8*)out + B_LO_OFF;
    const float*  enh = ws + WS_ENH;

    float b1[4][4], b2[4][4]; int i1[4][4], i2[4][4];
#pragma unroll
    for (int mt = 0; mt < 4; ++mt)
#pragma unroll
        for (int r = 0; r < 4; ++r) {
            b1[mt][r] = 3.4e38f; b2[mt][r] = 3.4e38f;
            i1[mt][r] = 0;       i2[mt][r] = 0;
        }

    // register ping-pong prefetch of B fragments
    short8 cbh0[2], cbh1[2], cbl0[2], cbl1[2]; float cenh[2];
    cbh0[0] = bhp[lane];      cbh1[0] = bhp[64 + lane];
    cbl0[0] = blp[lane];      cbl1[0] = blp[64 + lane];
    cenh[0] = enh[col];

#pragma unroll 2
    for (int t = 0; t < 32; ++t) {
        const int cur = t & 1, nxt = cur ^ 1;
        if (t + 1 < 32) {
            int o = (t + 1) * 128;
            cbh0[nxt] = bhp[o + lane];      cbh1[nxt] = bhp[o + 64 + lane];
            cbl0[nxt] = blp[o + lane];      cbl1[nxt] = blp[o + 64 + lane];
            cenh[nxt] = enh[(t + 1) * 16 + col];
        }
        const float ev = cenh[cur];
        const int codev = t * 16 + col;
#pragma unroll
        for (int mt = 0; mt < 4; ++mt) {
            f32x4 acc = { ev, ev, ev, ev };
            acc = __builtin_amdgcn_mfma_f32_16x16x32_bf16(ah[mt][0], cbh0[cur], acc, 0, 0, 0);
            acc = __builtin_amdgcn_mfma_f32_16x16x32_bf16(al[mt][0], cbh0[cur], acc, 0, 0, 0);
            acc = __builtin_amdgcn_mfma_f32_16x16x32_bf16(ah[mt][0], cbl0[cur], acc, 0, 0, 0);
            acc = __builtin_amdgcn_mfma_f32_16x16x32_bf16(al[mt][0], cbl0[cur], acc, 0, 0, 0);
            acc = __builtin_amdgcn_mfma_f32_16x16x32_bf16(ah[mt][1], cbh1[cur], acc, 0, 0, 0);
            acc = __builtin_amdgcn_mfma_f32_16x16x32_bf16(al[mt][1], cbh1[cur], acc, 0, 0, 0);
            acc = __builtin_amdgcn_mfma_f32_16x16x32_bf16(ah[mt][1], cbl1[cur], acc, 0, 0, 0);
            acc = __builtin_amdgcn_mfma_f32_16x16x32_bf16(al[mt][1], cbl1[cur], acc, 0, 0, 0);
#pragma unroll
            for (int r = 0; r < 4; ++r) {
                float v = acc[r];
                bool lt  = v < b1[mt][r];
                float lv = lt ? b1[mt][r] : v;
                int   li = lt ? i1[mt][r] : codev;
                b1[mt][r] = lt ? v : b1[mt][r];
                i1[mt][r] = lt ? codev : i1[mt][r];
                bool lt2 = lv < b2[mt][r];
                b2[mt][r] = lt2 ? lv : b2[mt][r];
                i2[mt][r] = lt2 ? li : i2[mt][r];
            }
        }
    }

    // cross-lane top-2 merge over the 16 code-columns, then write packed pair
    unsigned* outu = (unsigned*)out;
#pragma unroll
    for (int mt = 0; mt < 4; ++mt)
#pragma unroll
        for (int r = 0; r < 4; ++r) {
            float vb1 = b1[mt][r], vb2 = b2[mt][r];
            int   vi1 = i1[mt][r], vi2 = i2[mt][r];
#pragma unroll
            for (int m = 1; m < 16; m <<= 1) {
                float ob1 = __shfl_xor(vb1, m, 16);
                float ob2 = __shfl_xor(vb2, m, 16);
                int   oi1 = __shfl_xor(vi1, m, 16);
                int   oi2 = __shfl_xor(vi2, m, 16);
                bool lt   = ob1 < vb1;
                float nb1 = lt ? ob1 : vb1;  int ni1 = lt ? oi1 : vi1;
                float l1v = lt ? vb1 : ob1;  int l1i = lt ? vi1 : oi1;
                float cb2 = lt ? ob2 : vb2;  int ci2 = lt ? oi2 : vi2;
                bool lt2  = cb2 < l1v;
                vb2 = lt2 ? cb2 : l1v;  vi2 = lt2 ? ci2 : l1i;
                vb1 = nb1;              vi1 = ni1;
            }
            if (col == r) {
                int p = pixw + mt * 16 + rowg * 4 + r;
                outu[I_OFF + p] = (unsigned)vi1 | ((unsigned)vi2 << 16);
            }
        }
}

// ----------------------------------------------------------------- out ----
// Exact fp32 recheck of the two candidates (numerics identical in class to
// the round-2 kernel that passed), gather + quantized write + loss partials.
__device__ __forceinline__ float dotrow(const float* __restrict__ er,
                                        const float* __restrict__ xv) {
    const float4* e4 = (const float4*)er;
    float a0 = 0.f, a1 = 0.f, a2 = 0.f, a3 = 0.f;
#pragma unroll
    for (int q = 0; q < 16; ++q) {
        float4 e = e4[q];
        a0 = fmaf(xv[4*q+0], e.x, a0);
        a1 = fmaf(xv[4*q+1], e.y, a1);
        a2 = fmaf(xv[4*q+2], e.z, a2);
        a3 = fmaf(xv[4*q+3], e.w, a3);
    }
    return (a0 + a1) + (a2 + a3);
}

__global__ __launch_bounds__(256) void vq_out(const float* __restrict__ x,
                                              const float* __restrict__ ws,
                                              float* __restrict__ out,
                                              float* __restrict__ partial) {
    const float* ET = ws + WS_ET;
    const float* EN = ws + WS_EN;
    int n  = blockIdx.x * 256 + threadIdx.x;
    int b  = n >> 12;
    int hw = n & 4095;

    const float* xp = x + ((size_t)b << 18) + hw;
    float xv[D];
#pragma unroll
    for (int d = 0; d < D; ++d) xv[d] = xp[(size_t)d << 12];

    unsigned packed = ((const unsigned*)out)[I_OFF + n];
    int c1 = (int)(packed & 0xffffu), c2 = (int)(packed >> 16);

    float d1 = fmaf(-2.f, dotrow(ET + (c1 << 6), xv), EN[c1]);
    float d2 = fmaf(-2.f, dotrow(ET + (c2 << 6), xv), EN[c2]);
    bool sw = (d2 < d1) || (d2 == d1 && c2 < c1);   // np.argmin: first min wins
    int bestk = sw ? c2 : c1;

    out[I_OFF + n] = (float)bestk;

    const float* qv = ET + (bestk << 6);
    float* op = out + Q_OFF + ((size_t)b << 18) + hw;
    float lsum = 0.f;
#pragma unroll
    for (int d = 0; d < D; ++d) {
        float qd = qv[d];
        op[(size_t)d << 12] = qd;
        float diff = xv[d] - qd;
        lsum = fmaf(diff, diff, lsum);
    }

#pragma unroll
    for (int off = 32; off > 0; off >>= 1)
        lsum += __shfl_down(lsum, off, 64);
    __shared__ float wsum[4];
    if ((threadIdx.x & 63) == 0) wsum[threadIdx.x >> 6] = lsum;
    __syncthreads();
    if (threadIdx.x == 0)
        partial[blockIdx.x] = (wsum[0] + wsum[1]) + (wsum[2] + wsum[3]);
}

__global__ __launch_bounds__(256) void vq_final(const float* __restrict__ partial,
                                                float* __restrict__ out) {
    int t = threadIdx.x;
    float s = partial[t] + partial[t + 256];
#pragma unroll
    for (int off = 32; off > 0; off >>= 1)
        s += __shfl_down(s, off, 64);
    __shared__ float wsum[4];
    if ((t & 63) == 0) wsum[t >> 6] = s;
    __syncthreads();
    if (t == 0)
        out[L_OFF] = ((wsum[0] + wsum[1]) + (wsum[2] + wsum[3])) * (1.f / 8388608.f);
}

extern "C" void kernel_launch(void* const* d_in, const int* in_sizes, int n_in,
                              void* d_out, int out_size, void* d_ws, size_t ws_size,
                              hipStream_t stream) {
    const float* x = (const float*)d_in[0];
    const float* E = (const float*)d_in[1];
    float* out = (float*)d_out;
    float* ws  = (float*)d_ws;

    hipLaunchKernelGGL(vq_prep,  dim3(8),   dim3(256), 0, stream, E, ws, out);
    hipLaunchKernelGGL(vq_dist,  dim3(512), dim3(256), 0, stream, x, ws, out);
    hipLaunchKernelGGL(vq_out,   dim3(512), dim3(256), 0, stream, x, ws, out, ws + WS_PART);
    hipLaunchKernelGGL(vq_final, dim3(1),   dim3(256), 0, stream, ws + WS_PART, out);
}

// Round 6
// 71.161 us; speedup vs baseline: 4.1961x; 1.0568x over previous
//
#include <hip/hip_runtime.h>

#define D      64
#define K      512
#define Q_OFF  0            // out[0 .. 8388607]   quantized_ste (NCHW)
#define L_OFF  8388608      // out[8388608]        commitment loss
#define I_OFF  8388609      // out[8388609 .. ]    indices (131072)

// ws layout (floats)
#define WS_ET    0          // 512*64 transposed embeddings (fp32, exact)
#define WS_EN    32768      // 512 ||e||^2
#define WS_ENH   33280      // 512 0.5*||e||^2
#define WS_PART  33792      // partial loss sums (1024)

// B-fragment tables staged in out[] (quantized region, rewritten later):
// hi at short8[0..4095], lo at short8[4096..8191]  (64 KB each)
#define B_LO_OFF 4096

typedef __attribute__((ext_vector_type(8))) short short8;   // 8 bf16 = 4 VGPRs
typedef __attribute__((ext_vector_type(4))) float f32x4;

static __device__ __forceinline__ unsigned short f2bf(float f) {
    unsigned u = __float_as_uint(f);
    u += 0x7fffu + ((u >> 16) & 1u);       // RTN-even
    return (unsigned short)(u >> 16);
}
static __device__ __forceinline__ float bf2f(unsigned short h) {
    return __uint_as_float(((unsigned)h) << 16);
}

// ---------------------------------------------------------------- prep ----
// Packs B-operand fragments of (-e) in hi/lo bf16 into the (temporarily
// unused) quantized region of `out`: layout [tile t:32][kstep s:2][lane:64]
// of short8; slot j holds (-E)[k = s*32 + (lane>>4)*8 + j][code = t*16+(lane&15)].
// Also builds ET (fp32 transpose) + ||e||^2 tables in ws.
__global__ __launch_bounds__(256) void vq_prep(const float* __restrict__ E,
                                               float* __restrict__ ws,
                                               float* __restrict__ out) {
    int g = blockIdx.x * 256 + threadIdx.x;   // 0..2047 = (t, lane)
    int t = g >> 6, lane = g & 63;
    int col = lane & 15, kg = lane >> 4;
    int code = t * 16 + col;
    short8* bhp = (short8*)out;               // 64 KB
    short8* blp = (short8*)out + B_LO_OFF;    // next 64 KB
#pragma unroll
    for (int s = 0; s < 2; ++s) {
        short8 h, l;
#pragma unroll
        for (int j = 0; j < 8; ++j) {
            int k = s * 32 + kg * 8 + j;
            float v = -E[k * K + code];
            unsigned short hb = f2bf(v);
            h[j] = (short)hb;
            l[j] = (short)f2bf(v - bf2f(hb));
        }
        bhp[(t * 2 + s) * 64 + lane] = h;
        blp[(t * 2 + s) * 64 + lane] = l;
    }
    if (g < K) {
        float nsq = 0.f;
#pragma unroll 8
        for (int d = 0; d < D; ++d) {
            float v = E[d * K + g];
            ws[WS_ET + g * D + d] = v;
            nsq = fmaf(v, v, nsq);
        }
        ws[WS_EN + g]  = nsq;
        ws[WS_ENH + g] = 0.5f * nsq;
    }
}

// ---------------------------------------------------------------- dist ----
// Block = 256 thr = 4 waves; wave owns 32 pixels (2 M-tiles of 16) x all 512
// codes (32 N-tiles of 16).  acc init = 0.5*||e||^2, A = x (hi+lo bf16),
// B = -e (hi+lo); lo*lo pass dropped (error ~3e-5, covered by exact top-2
// recheck)  =>  acc ~= 0.5*||e||^2 - x.e  (same argmin as distance).
// Tracks top-2 (value, index) per pixel, cross-lane merges, writes packed
// (i1 | i2<<16) into out's index slots for the recheck kernel.
__global__ __launch_bounds__(256, 2) void vq_dist(const float* __restrict__ x,
                                                  const float* __restrict__ ws,
                                                  float* __restrict__ out) {
    const int tid = threadIdx.x, w = tid >> 6, lane = tid & 63;
    const int col = lane & 15, rowg = lane >> 4;
    const int pixw = blockIdx.x * 128 + w * 32;

    // ---- load x fragments and split to bf16 hi/lo: A[mt][s]
    short8 ah[2][2], al[2][2];
#pragma unroll
    for (int mt = 0; mt < 2; ++mt) {
        int pix = pixw + mt * 16 + col;
        const float* xp = x + ((size_t)(pix >> 12) << 18) + (pix & 4095);
#pragma unroll
        for (int s = 0; s < 2; ++s) {
            short8 h, l;
#pragma unroll
            for (int j = 0; j < 8; ++j) {
                float v = xp[(size_t)(s * 32 + rowg * 8 + j) << 12];
                unsigned short hb = f2bf(v);
                h[j] = (short)hb;
                l[j] = (short)f2bf(v - bf2f(hb));
            }
            ah[mt][s] = h; al[mt][s] = l;
        }
    }

    const short8* bhp = (const short8*)out;
    const short8* blp = (const short8*)out + B_LO_OFF;
    const float*  enh = ws + WS_ENH;

    float b1[2][4], b2[2][4]; int i1[2][4], i2[2][4];
#pragma unroll
    for (int mt = 0; mt < 2; ++mt)
#pragma unroll
        for (int r = 0; r < 4; ++r) {
            b1[mt][r] = 3.4e38f; b2[mt][r] = 3.4e38f;
            i1[mt][r] = 0;       i2[mt][r] = 0;
        }

    // register ping-pong prefetch of B fragments
    short8 cbh0[2], cbh1[2], cbl0[2], cbl1[2]; float cenh[2];
    cbh0[0] = bhp[lane];      cbh1[0] = bhp[64 + lane];
    cbl0[0] = blp[lane];      cbl1[0] = blp[64 + lane];
    cenh[0] = enh[col];

#pragma unroll 2
    for (int t = 0; t < 32; ++t) {
        const int cur = t & 1, nxt = cur ^ 1;
        if (t + 1 < 32) {
            int o = (t + 1) * 128;
            cbh0[nxt] = bhp[o + lane];      cbh1[nxt] = bhp[o + 64 + lane];
            cbl0[nxt] = blp[o + lane];      cbl1[nxt] = blp[o + 64 + lane];
            cenh[nxt] = enh[(t + 1) * 16 + col];
        }
        const float ev = cenh[cur];
        const int codev = t * 16 + col;
#pragma unroll
        for (int mt = 0; mt < 2; ++mt) {
            f32x4 acc = { ev, ev, ev, ev };
            acc = __builtin_amdgcn_mfma_f32_16x16x32_bf16(ah[mt][0], cbh0[cur], acc, 0, 0, 0);
            acc = __builtin_amdgcn_mfma_f32_16x16x32_bf16(al[mt][0], cbh0[cur], acc, 0, 0, 0);
            acc = __builtin_amdgcn_mfma_f32_16x16x32_bf16(ah[mt][0], cbl0[cur], acc, 0, 0, 0);
            acc = __builtin_amdgcn_mfma_f32_16x16x32_bf16(ah[mt][1], cbh1[cur], acc, 0, 0, 0);
            acc = __builtin_amdgcn_mfma_f32_16x16x32_bf16(al[mt][1], cbh1[cur], acc, 0, 0, 0);
            acc = __builtin_amdgcn_mfma_f32_16x16x32_bf16(ah[mt][1], cbl1[cur], acc, 0, 0, 0);
#pragma unroll
            for (int r = 0; r < 4; ++r) {
                float v = acc[r];
                bool lt  = v < b1[mt][r];
                float lv = lt ? b1[mt][r] : v;
                int   li = lt ? i1[mt][r] : codev;
                b1[mt][r] = lt ? v : b1[mt][r];
                i1[mt][r] = lt ? codev : i1[mt][r];
                bool lt2 = lv < b2[mt][r];
                b2[mt][r] = lt2 ? lv : b2[mt][r];
                i2[mt][r] = lt2 ? li : i2[mt][r];
            }
        }
    }

    // cross-lane top-2 merge over the 16 code-columns, then write packed pair
    unsigned* outu = (unsigned*)out;
#pragma unroll
    for (int mt = 0; mt < 2; ++mt)
#pragma unroll
        for (int r = 0; r < 4; ++r) {
            float vb1 = b1[mt][r], vb2 = b2[mt][r];
            int   vi1 = i1[mt][r], vi2 = i2[mt][r];
#pragma unroll
            for (int m = 1; m < 16; m <<= 1) {
                float ob1 = __shfl_xor(vb1, m, 16);
                float ob2 = __shfl_xor(vb2, m, 16);
                int   oi1 = __shfl_xor(vi1, m, 16);
                int   oi2 = __shfl_xor(vi2, m, 16);
                bool lt   = ob1 < vb1;
                float nb1 = lt ? ob1 : vb1;  int ni1 = lt ? oi1 : vi1;
                float l1v = lt ? vb1 : ob1;  int l1i = lt ? vi1 : oi1;
                float cb2 = lt ? ob2 : vb2;  int ci2 = lt ? oi2 : vi2;
                bool lt2  = cb2 < l1v;
                vb2 = lt2 ? cb2 : l1v;  vi2 = lt2 ? ci2 : l1i;
                vb1 = nb1;              vi1 = ni1;
            }
            if (col == r) {
                int p = pixw + mt * 16 + rowg * 4 + r;
                outu[I_OFF + p] = (unsigned)vi1 | ((unsigned)vi2 << 16);
            }
        }
}

// ----------------------------------------------------------------- out ----
// Exact fp32 recheck of the two candidates (numerics identical in class to
// the round-2 kernel that passed), gather + quantized write + loss partials.
__device__ __forceinline__ float dotrow(const float* __restrict__ er,
                                        const float* __restrict__ xv) {
    const float4* e4 = (const float4*)er;
    float a0 = 0.f, a1 = 0.f, a2 = 0.f, a3 = 0.f;
#pragma unroll
    for (int q = 0; q < 16; ++q) {
        float4 e = e4[q];
        a0 = fmaf(xv[4*q+0], e.x, a0);
        a1 = fmaf(xv[4*q+1], e.y, a1);
        a2 = fmaf(xv[4*q+2], e.z, a2);
        a3 = fmaf(xv[4*q+3], e.w, a3);
    }
    return (a0 + a1) + (a2 + a3);
}

__global__ __launch_bounds__(256) void vq_out(const float* __restrict__ x,
                                              const float* __restrict__ ws,
                                              float* __restrict__ out,
                                              float* __restrict__ partial) {
    const float* ET = ws + WS_ET;
    const float* EN = ws + WS_EN;
    int n  = blockIdx.x * 256 + threadIdx.x;
    int b  = n >> 12;
    int hw = n & 4095;

    const float* xp = x + ((size_t)b << 18) + hw;
    float xv[D];
#pragma unroll
    for (int d = 0; d < D; ++d) xv[d] = xp[(size_t)d << 12];

    unsigned packed = ((const unsigned*)out)[I_OFF + n];
    int c1 = (int)(packed & 0xffffu), c2 = (int)(packed >> 16);

    float d1 = fmaf(-2.f, dotrow(ET + (c1 << 6), xv), EN[c1]);
    float d2 = fmaf(-2.f, dotrow(ET + (c2 << 6), xv), EN[c2]);
    bool sw = (d2 < d1) || (d2 == d1 && c2 < c1);   // np.argmin: first min wins
    int bestk = sw ? c2 : c1;

    out[I_OFF + n] = (float)bestk;

    const float* qv = ET + (bestk << 6);
    float* op = out + Q_OFF + ((size_t)b << 18) + hw;
    float lsum = 0.f;
#pragma unroll
    for (int d = 0; d < D; ++d) {
        float qd = qv[d];
        op[(size_t)d << 12] = qd;
        float diff = xv[d] - qd;
        lsum = fmaf(diff, diff, lsum);
    }

#pragma unroll
    for (int off = 32; off > 0; off >>= 1)
        lsum += __shfl_down(lsum, off, 64);
    __shared__ float wsum[4];
    if ((threadIdx.x & 63) == 0) wsum[threadIdx.x >> 6] = lsum;
    __syncthreads();
    if (threadIdx.x == 0)
        partial[blockIdx.x] = (wsum[0] + wsum[1]) + (wsum[2] + wsum[3]);
}

__global__ __launch_bounds__(256) void vq_final(const float* __restrict__ partial,
                                                float* __restrict__ out) {
    int t = threadIdx.x;
    float s = partial[t] + partial[t + 256];
#pragma unroll
    for (int off = 32; off > 0; off >>= 1)
        s += __shfl_down(s, off, 64);
    __shared__ float wsum[4];
    if ((t & 63) == 0) wsum[t >> 6] = s;
    __syncthreads();
    if (t == 0)
        out[L_OFF] = ((wsum[0] + wsum[1]) + (wsum[2] + wsum[3])) * (1.f / 8388608.f);
}

extern "C" void kernel_launch(void* const* d_in, const int* in_sizes, int n_in,
                              void* d_out, int out_size, void* d_ws, size_t ws_size,
                              hipStream_t stream) {
    const float* x = (const float*)d_in[0];
    const float* E = (const float*)d_in[1];
    float* out = (float*)d_out;
    float* ws  = (float*)d_ws;

    hipLaunchKernelGGL(vq_prep,  dim3(8),    dim3(256), 0, stream, E, ws, out);
    hipLaunchKernelGGL(vq_dist,  dim3(1024), dim3(256), 0, stream, x, ws, out);
    hipLaunchKernelGGL(vq_out,   dim3(512),  dim3(256), 0, stream, x, ws, out, ws + WS_PART);
    hipLaunchKernelGGL(vq_final, dim3(1),    dim3(256), 0, stream, ws + WS_PART, out);
}

// Round 7
// 65.822 us; speedup vs baseline: 4.5365x; 1.0811x over previous
//
#include <hip/hip_runtime.h>

#define D      64
#define K      512
#define Q_OFF  0            // out[0 .. 8388607]   quantized_ste (NCHW)
#define L_OFF  8388608      // out[8388608]        commitment loss
#define I_OFF  8388609      // out[8388609 .. ]    indices (131072)

// ws layout (floats)
#define WS_ET    0          // 512*64 transposed embeddings (fp32, exact)
#define WS_EN    32768      // 512 ||e||^2
#define WS_ENH   33280      // 512 0.5*||e||^2
#define WS_PART  33792      // partial loss sums

// B-fragment tables staged in out[] (quantized region, rewritten later)
#define B_LO_OFF 4096

// packed fixed-point selection constants
#define SEL_SCALE 16384.0f              // 2^14: resolution 6.1e-5
#define SEL_BIAS  (160.0f * 16384.0f)   // acc in (-160, 256) -> positive

typedef __attribute__((ext_vector_type(8))) short short8;   // 8 bf16 = 4 VGPRs
typedef __attribute__((ext_vector_type(4))) float f32x4;

static __device__ __forceinline__ unsigned short f2bf(float f) {
    unsigned u = __float_as_uint(f);
    u += 0x7fffu + ((u >> 16) & 1u);       // RTN-even
    return (unsigned short)(u >> 16);
}
static __device__ __forceinline__ float bf2f(unsigned short h) {
    return __uint_as_float(((unsigned)h) << 16);
}

// ---------------------------------------------------------------- prep ----
__global__ __launch_bounds__(256) void vq_prep(const float* __restrict__ E,
                                               float* __restrict__ ws,
                                               float* __restrict__ out) {
    int g = blockIdx.x * 256 + threadIdx.x;   // 0..2047 = (t, lane)
    int t = g >> 6, lane = g & 63;
    int col = lane & 15, kg = lane >> 4;
    int code = t * 16 + col;
    short8* bhp = (short8*)out;               // 64 KB
    short8* blp = (short8*)out + B_LO_OFF;    // next 64 KB
#pragma unroll
    for (int s = 0; s < 2; ++s) {
        short8 h, l;
#pragma unroll
        for (int j = 0; j < 8; ++j) {
            int k = s * 32 + kg * 8 + j;
            float v = -E[k * K + code];
            unsigned short hb = f2bf(v);
            h[j] = (short)hb;
            l[j] = (short)f2bf(v - bf2f(hb));
        }
        bhp[(t * 2 + s) * 64 + lane] = h;
        blp[(t * 2 + s) * 64 + lane] = l;
    }
    if (g < K) {
        float nsq = 0.f;
#pragma unroll 8
        for (int d = 0; d < D; ++d) {
            float v = E[d * K + g];
            ws[WS_ET + g * D + d] = v;
            nsq = fmaf(v, v, nsq);
        }
        ws[WS_EN + g]  = nsq;
        ws[WS_ENH + g] = 0.5f * nsq;
    }
}

// ---------------------------------------------------------------- dist ----
// Wave owns 32 pixels (2 M-tiles) x 512 codes. acc = 0.5||e||^2 - x.e via
// 3-pass split-bf16 MFMA. Selection: packed fixed-point top-2
// (dist<<9 | code) with v_min_u32 — monotone, first-min-wins like np.argmin.
__global__ __launch_bounds__(256, 2) void vq_dist(const float* __restrict__ x,
                                                  const float* __restrict__ ws,
                                                  float* __restrict__ out) {
    const int tid = threadIdx.x, w = tid >> 6, lane = tid & 63;
    const int col = lane & 15, rowg = lane >> 4;
    const int pixw = blockIdx.x * 128 + w * 32;

    // ---- load x fragments and split to bf16 hi/lo: A[mt][s]
    short8 ah[2][2], al[2][2];
#pragma unroll
    for (int mt = 0; mt < 2; ++mt) {
        int pix = pixw + mt * 16 + col;
        const float* xp = x + ((size_t)(pix >> 12) << 18) + (pix & 4095);
#pragma unroll
        for (int s = 0; s < 2; ++s) {
            short8 h, l;
#pragma unroll
            for (int j = 0; j < 8; ++j) {
                float v = xp[(size_t)(s * 32 + rowg * 8 + j) << 12];
                unsigned short hb = f2bf(v);
                h[j] = (short)hb;
                l[j] = (short)f2bf(v - bf2f(hb));
            }
            ah[mt][s] = h; al[mt][s] = l;
        }
    }

    const short8* bhp = (const short8*)out;
    const short8* blp = (const short8*)out + B_LO_OFF;
    const float*  enh = ws + WS_ENH;

    unsigned m1[2][4], m2[2][4];
#pragma unroll
    for (int mt = 0; mt < 2; ++mt)
#pragma unroll
        for (int r = 0; r < 4; ++r) { m1[mt][r] = 0xFFFFFFFFu; m2[mt][r] = 0xFFFFFFFFu; }

    // B-fragment register pipeline, prefetch distance 2 (2 buffers)
    short8 pbh0[2], pbh1[2], pbl0[2], pbl1[2]; float pev[2];
    pbh0[0] = bhp[lane];        pbh1[0] = bhp[64 + lane];
    pbl0[0] = blp[lane];        pbl1[0] = blp[64 + lane];
    pev[0]  = enh[col];
    pbh0[1] = bhp[128 + lane];  pbh1[1] = bhp[192 + lane];
    pbl0[1] = blp[128 + lane];  pbl1[1] = blp[192 + lane];
    pev[1]  = enh[16 + col];

#pragma unroll 2
    for (int t = 0; t < 32; ++t) {
        const int cur = t & 1;
        const float ev = pev[cur];
        const unsigned codev = (unsigned)(t * 16 + col);

        f32x4 acc0 = { ev, ev, ev, ev };
        f32x4 acc1 = { ev, ev, ev, ev };
        acc0 = __builtin_amdgcn_mfma_f32_16x16x32_bf16(ah[0][0], pbh0[cur], acc0, 0, 0, 0);
        acc0 = __builtin_amdgcn_mfma_f32_16x16x32_bf16(al[0][0], pbh0[cur], acc0, 0, 0, 0);
        acc0 = __builtin_amdgcn_mfma_f32_16x16x32_bf16(ah[0][0], pbl0[cur], acc0, 0, 0, 0);
        acc0 = __builtin_amdgcn_mfma_f32_16x16x32_bf16(ah[0][1], pbh1[cur], acc0, 0, 0, 0);
        acc0 = __builtin_amdgcn_mfma_f32_16x16x32_bf16(al[0][1], pbh1[cur], acc0, 0, 0, 0);
        acc0 = __builtin_amdgcn_mfma_f32_16x16x32_bf16(ah[0][1], pbl1[cur], acc0, 0, 0, 0);
        acc1 = __builtin_amdgcn_mfma_f32_16x16x32_bf16(ah[1][0], pbh0[cur], acc1, 0, 0, 0);
        acc1 = __builtin_amdgcn_mfma_f32_16x16x32_bf16(al[1][0], pbh0[cur], acc1, 0, 0, 0);
        acc1 = __builtin_amdgcn_mfma_f32_16x16x32_bf16(ah[1][0], pbl0[cur], acc1, 0, 0, 0);
        acc1 = __builtin_amdgcn_mfma_f32_16x16x32_bf16(ah[1][1], pbh1[cur], acc1, 0, 0, 0);
        acc1 = __builtin_amdgcn_mfma_f32_16x16x32_bf16(al[1][1], pbh1[cur], acc1, 0, 0, 0);
        acc1 = __builtin_amdgcn_mfma_f32_16x16x32_bf16(ah[1][1], pbl1[cur], acc1, 0, 0, 0);

        // prefetch t+2 into the buffer consumed this iteration
        if (t + 2 < 32) {
            int o = (t + 2) * 128;
            pbh0[cur] = bhp[o + lane];      pbh1[cur] = bhp[o + 64 + lane];
            pbl0[cur] = blp[o + lane];      pbl1[cur] = blp[o + 64 + lane];
            pev[cur]  = enh[(t + 2) * 16 + col];
        }

        // packed top-2 update: 6 VALU per acc element
#pragma unroll
        for (int r = 0; r < 4; ++r) {
            unsigned u0 = (unsigned)fmaf(acc0[r], SEL_SCALE, SEL_BIAS);
            unsigned p0 = (u0 << 9) + codev;
            m2[0][r] = min(m2[0][r], max(m1[0][r], p0));
            m1[0][r] = min(m1[0][r], p0);
            unsigned u1 = (unsigned)fmaf(acc1[r], SEL_SCALE, SEL_BIAS);
            unsigned p1 = (u1 << 9) + codev;
            m2[1][r] = min(m2[1][r], max(m1[1][r], p1));
            m1[1][r] = min(m1[1][r], p1);
        }
    }

    // cross-lane top-2 merge over the 16 code-columns, write packed (c1|c2<<16)
    unsigned* outu = (unsigned*)out;
#pragma unroll
    for (int mt = 0; mt < 2; ++mt)
#pragma unroll
        for (int r = 0; r < 4; ++r) {
            unsigned v1 = m1[mt][r], v2 = m2[mt][r];
#pragma unroll
            for (int m = 1; m < 16; m <<= 1) {
                unsigned o1 = (unsigned)__shfl_xor((int)v1, m, 16);
                unsigned o2 = (unsigned)__shfl_xor((int)v2, m, 16);
                v2 = min(max(v1, o1), min(v2, o2));
                v1 = min(v1, o1);
            }
            if (col == r) {
                int p = pixw + mt * 16 + rowg * 4 + r;
                unsigned c1 = v1 & 511u, c2 = v2 & 511u;
                outu[I_OFF + p] = c1 | (c2 << 16);
            }
        }
}

// ----------------------------------------------------------------- out ----
__device__ __forceinline__ float dotrow(const float* __restrict__ er,
                                        const float* __restrict__ xv) {
    const float4* e4 = (const float4*)er;
    float a0 = 0.f, a1 = 0.f, a2 = 0.f, a3 = 0.f;
#pragma unroll
    for (int q = 0; q < 16; ++q) {
        float4 e = e4[q];
        a0 = fmaf(xv[4*q+0], e.x, a0);
        a1 = fmaf(xv[4*q+1], e.y, a1);
        a2 = fmaf(xv[4*q+2], e.z, a2);
        a3 = fmaf(xv[4*q+3], e.w, a3);
    }
    return (a0 + a1) + (a2 + a3);
}

__global__ __launch_bounds__(256) void vq_out(const float* __restrict__ x,
                                              const float* __restrict__ ws,
                                              float* __restrict__ out,
                                              float* __restrict__ partial) {
    const float* ET = ws + WS_ET;
    const float* EN = ws + WS_EN;
    int n  = blockIdx.x * 256 + threadIdx.x;
    int b  = n >> 12;
    int hw = n & 4095;

    const float* xp = x + ((size_t)b << 18) + hw;
    float xv[D];
#pragma unroll
    for (int d = 0; d < D; ++d) xv[d] = xp[(size_t)d << 12];

    unsigned packed = ((const unsigned*)out)[I_OFF + n];
    int c1 = (int)(packed & 0xffffu), c2 = (int)(packed >> 16);

    float d1 = fmaf(-2.f, dotrow(ET + (c1 << 6), xv), EN[c1]);
    float d2 = fmaf(-2.f, dotrow(ET + (c2 << 6), xv), EN[c2]);
    bool sw = (d2 < d1) || (d2 == d1 && c2 < c1);   // np.argmin: first min wins
    int bestk = sw ? c2 : c1;

    out[I_OFF + n] = (float)bestk;

    const float* qv = ET + (bestk << 6);
    float* op = out + Q_OFF + ((size_t)b << 18) + hw;
    float lsum = 0.f;
#pragma unroll
    for (int d = 0; d < D; ++d) {
        float qd = qv[d];
        op[(size_t)d << 12] = qd;
        float diff = xv[d] - qd;
        lsum = fmaf(diff, diff, lsum);
    }

#pragma unroll
    for (int off = 32; off > 0; off >>= 1)
        lsum += __shfl_down(lsum, off, 64);
    __shared__ float wsum[4];
    if ((threadIdx.x & 63) == 0) wsum[threadIdx.x >> 6] = lsum;
    __syncthreads();
    if (threadIdx.x == 0)
        partial[blockIdx.x] = (wsum[0] + wsum[1]) + (wsum[2] + wsum[3]);
}

__global__ __launch_bounds__(256) void vq_final(const float* __restrict__ partial,
                                                float* __restrict__ out) {
    int t = threadIdx.x;
    float s = partial[t] + partial[t + 256];
#pragma unroll
    for (int off = 32; off > 0; off >>= 1)
        s += __shfl_down(s, off, 64);
    __shared__ float wsum[4];
    if ((t & 63) == 0) wsum[t >> 6] = s;
    __syncthreads();
    if (t == 0)
        out[L_OFF] = ((wsum[0] + wsum[1]) + (wsum[2] + wsum[3])) * (1.f / 8388608.f);
}

extern "C" void kernel_launch(void* const* d_in, const int* in_sizes, int n_in,
                              void* d_out, int out_size, void* d_ws, size_t ws_size,
                              hipStream_t stream) {
    const float* x = (const float*)d_in[0];
    const float* E = (const float*)d_in[1];
    float* out = (float*)d_out;
    float* ws  = (float*)d_ws;

    hipLaunchKernelGGL(vq_prep,  dim3(8),    dim3(256), 0, stream, E, ws, out);
    hipLaunchKernelGGL(vq_dist,  dim3(1024), dim3(256), 0, stream, x, ws, out);
    hipLaunchKernelGGL(vq_out,   dim3(512),  dim3(256), 0, stream, x, ws, out, ws + WS_PART);
    hipLaunchKernelGGL(vq_final, dim3(1),    dim3(256), 0, stream, ws + WS_PART, out);
}

// Round 8
// 65.181 us; speedup vs baseline: 4.5811x; 1.0098x over previous
//
#include <hip/hip_runtime.h>

#define D      64
#define K      512
#define Q_OFF  0            // out[0 .. 8388607]   quantized_ste (NCHW)
#define L_OFF  8388608      // out[8388608]        commitment loss
#define I_OFF  8388609      // out[8388609 .. ]    indices (131072)

// ws layout (floats)
#define WS_ET    0          // 512*64 transposed embeddings (fp32, exact)
#define WS_EN    32768      // 512 ||e||^2
#define WS_ENH   33280      // 512 0.5*||e||^2
#define WS_PART  33792      // partial loss sums

// B-fragment tables staged in out[] (quantized region, rewritten later)
#define B_LO_OFF 4096

// packed fixed-point selection constants
#define SEL_SCALE 16384.0f              // 2^14: resolution 6.1e-5
#define SEL_BIAS  (160.0f * 16384.0f)   // acc in (-160, 256) -> positive

typedef __attribute__((ext_vector_type(8))) short short8;   // 8 bf16 = 4 VGPRs
typedef __attribute__((ext_vector_type(4))) float f32x4;

static __device__ __forceinline__ unsigned short f2bf(float f) {
    unsigned u = __float_as_uint(f);
    u += 0x7fffu + ((u >> 16) & 1u);       // RTN-even
    return (unsigned short)(u >> 16);
}
static __device__ __forceinline__ float bf2f(unsigned short h) {
    return __uint_as_float(((unsigned)h) << 16);
}

// async global->LDS, 16 B per lane, linear layout (lds dest: wave base + lane*16)
__device__ __forceinline__ void gload_lds16(const float* g, float* l) {
    __builtin_amdgcn_global_load_lds(
        (const __attribute__((address_space(1))) unsigned int*)g,
        (__attribute__((address_space(3))) unsigned int*)l, 16, 0, 0);
}

// ---------------------------------------------------------------- prep ----
__global__ __launch_bounds__(256) void vq_prep(const float* __restrict__ E,
                                               float* __restrict__ ws,
                                               float* __restrict__ out) {
    int g = blockIdx.x * 256 + threadIdx.x;   // 0..2047 = (t, lane)
    int t = g >> 6, lane = g & 63;
    int col = lane & 15, kg = lane >> 4;
    int code = t * 16 + col;
    short8* bhp = (short8*)out;               // 64 KB
    short8* blp = (short8*)out + B_LO_OFF;    // next 64 KB
#pragma unroll
    for (int s = 0; s < 2; ++s) {
        short8 h, l;
#pragma unroll
        for (int j = 0; j < 8; ++j) {
            int k = s * 32 + kg * 8 + j;
            float v = -E[k * K + code];
            unsigned short hb = f2bf(v);
            h[j] = (short)hb;
            l[j] = (short)f2bf(v - bf2f(hb));
        }
        bhp[(t * 2 + s) * 64 + lane] = h;
        blp[(t * 2 + s) * 64 + lane] = l;
    }
    if (g < K) {
        float nsq = 0.f;
#pragma unroll 8
        for (int d = 0; d < D; ++d) {
            float v = E[d * K + g];
            ws[WS_ET + g * D + d] = v;
            nsq = fmaf(v, v, nsq);
        }
        ws[WS_EN + g]  = nsq;
        ws[WS_ENH + g] = 0.5f * nsq;
    }
}

// ---------------------------------------------------------------- dist ----
// 1024 blocks x 4 waves; wave owns 32 pixels (2 M-tiles) x 512 codes.
// B-fragments staged chunk-wise (2 code-tiles = 8 KB) into double-buffered
// LDS via global_load_lds, shared by the 4 waves; per-lane coalesced
// ds_read_b128 fragment reads. Selection: packed fixed-point top-2.
__global__ __launch_bounds__(256, 4) void vq_dist(const float* __restrict__ x,
                                                  const float* __restrict__ ws,
                                                  float* __restrict__ out) {
    __shared__ float sbuf[2][2048];           // 2 x 8 KB: hi [0,1024), lo [1024,2048)

    const int tid = threadIdx.x, w = tid >> 6, lane = tid & 63;
    const int col = lane & 15, rowg = lane >> 4;
    const int pixw = blockIdx.x * 128 + w * 32;

    // ---- load x fragments and split to bf16 hi/lo: A[mt][s]
    short8 ah[2][2], al[2][2];
#pragma unroll
    for (int mt = 0; mt < 2; ++mt) {
        int pix = pixw + mt * 16 + col;
        const float* xp = x + ((size_t)(pix >> 12) << 18) + (pix & 4095);
#pragma unroll
        for (int s = 0; s < 2; ++s) {
            short8 h, l;
#pragma unroll
            for (int j = 0; j < 8; ++j) {
                float v = xp[(size_t)(s * 32 + rowg * 8 + j) << 12];
                unsigned short hb = f2bf(v);
                h[j] = (short)hb;
                l[j] = (short)f2bf(v - bf2f(hb));
            }
            ah[mt][s] = h; al[mt][s] = l;
        }
    }

    const float* bh = (const float*)out;                       // hi table
    const float* bl = (const float*)out + B_LO_OFF * 4;        // lo table
    const float* enh = ws + WS_ENH;

    unsigned m1[2][4], m2[2][4];
#pragma unroll
    for (int mt = 0; mt < 2; ++mt)
#pragma unroll
        for (int r = 0; r < 4; ++r) { m1[mt][r] = 0xFFFFFFFFu; m2[mt][r] = 0xFFFFFFFFu; }

    // stage chunk 0 (code-tiles 0,1)
    gload_lds16(bh + tid * 4, &sbuf[0][tid * 4]);
    gload_lds16(bl + tid * 4, &sbuf[0][1024 + tid * 4]);
    __syncthreads();

    float pev = enh[col];                      // 0.5*||e||^2 prefetch (t=0)

    for (int c = 0; c < 16; ++c) {
        // prefetch chunk c+1 into the other buffer
        if (c + 1 < 16) {
            const float* sh = bh + (c + 1) * 1024 + tid * 4;
            const float* sl = bl + (c + 1) * 1024 + tid * 4;
            float* db = sbuf[(c + 1) & 1];
            gload_lds16(sh, db + tid * 4);
            gload_lds16(sl, db + 1024 + tid * 4);
        }

        const short8* sb = (const short8*)sbuf[c & 1];
#pragma unroll
        for (int p = 0; p < 2; ++p) {
            const int t = c * 2 + p;
            const float ev = pev;
            pev = (t + 1 < 32) ? enh[(t + 1) * 16 + col] : 0.f;
            const unsigned codev = (unsigned)(t * 16 + col);

            short8 cbh0 = sb[p * 128 + lane];
            short8 cbh1 = sb[p * 128 + 64 + lane];
            short8 cbl0 = sb[256 + p * 128 + lane];
            short8 cbl1 = sb[256 + p * 128 + 64 + lane];

            f32x4 acc0 = { ev, ev, ev, ev };
            f32x4 acc1 = { ev, ev, ev, ev };
            acc0 = __builtin_amdgcn_mfma_f32_16x16x32_bf16(ah[0][0], cbh0, acc0, 0, 0, 0);
            acc0 = __builtin_amdgcn_mfma_f32_16x16x32_bf16(al[0][0], cbh0, acc0, 0, 0, 0);
            acc0 = __builtin_amdgcn_mfma_f32_16x16x32_bf16(ah[0][0], cbl0, acc0, 0, 0, 0);
            acc0 = __builtin_amdgcn_mfma_f32_16x16x32_bf16(ah[0][1], cbh1, acc0, 0, 0, 0);
            acc0 = __builtin_amdgcn_mfma_f32_16x16x32_bf16(al[0][1], cbh1, acc0, 0, 0, 0);
            acc0 = __builtin_amdgcn_mfma_f32_16x16x32_bf16(ah[0][1], cbl1, acc0, 0, 0, 0);
            acc1 = __builtin_amdgcn_mfma_f32_16x16x32_bf16(ah[1][0], cbh0, acc1, 0, 0, 0);
            acc1 = __builtin_amdgcn_mfma_f32_16x16x32_bf16(al[1][0], cbh0, acc1, 0, 0, 0);
            acc1 = __builtin_amdgcn_mfma_f32_16x16x32_bf16(ah[1][0], cbl0, acc1, 0, 0, 0);
            acc1 = __builtin_amdgcn_mfma_f32_16x16x32_bf16(ah[1][1], cbh1, acc1, 0, 0, 0);
            acc1 = __builtin_amdgcn_mfma_f32_16x16x32_bf16(al[1][1], cbh1, acc1, 0, 0, 0);
            acc1 = __builtin_amdgcn_mfma_f32_16x16x32_bf16(ah[1][1], cbl1, acc1, 0, 0, 0);

            // packed top-2 update: 6 VALU per acc element
#pragma unroll
            for (int r = 0; r < 4; ++r) {
                unsigned u0 = (unsigned)fmaf(acc0[r], SEL_SCALE, SEL_BIAS);
                unsigned p0 = (u0 << 9) + codev;
                m2[0][r] = min(m2[0][r], max(m1[0][r], p0));
                m1[0][r] = min(m1[0][r], p0);
                unsigned u1 = (unsigned)fmaf(acc1[r], SEL_SCALE, SEL_BIAS);
                unsigned p1 = (u1 << 9) + codev;
                m2[1][r] = min(m2[1][r], max(m1[1][r], p1));
                m1[1][r] = min(m1[1][r], p1);
            }
        }
        __syncthreads();   // stage c+1 landed; all waves done with buf (c&1)
    }

    // cross-lane top-2 merge over the 16 code-columns, write packed (c1|c2<<16)
    unsigned* outu = (unsigned*)out;
#pragma unroll
    for (int mt = 0; mt < 2; ++mt)
#pragma unroll
        for (int r = 0; r < 4; ++r) {
            unsigned v1 = m1[mt][r], v2 = m2[mt][r];
#pragma unroll
            for (int m = 1; m < 16; m <<= 1) {
                unsigned o1 = (unsigned)__shfl_xor((int)v1, m, 16);
                unsigned o2 = (unsigned)__shfl_xor((int)v2, m, 16);
                v2 = min(max(v1, o1), min(v2, o2));
                v1 = min(v1, o1);
            }
            if (col == r) {
                int p = pixw + mt * 16 + rowg * 4 + r;
                unsigned c1 = v1 & 511u, c2 = v2 & 511u;
                outu[I_OFF + p] = c1 | (c2 << 16);
            }
        }
}

// ----------------------------------------------------------------- out ----
__device__ __forceinline__ float dotrow(const float* __restrict__ er,
                                        const float* __restrict__ xv) {
    const float4* e4 = (const float4*)er;
    float a0 = 0.f, a1 = 0.f, a2 = 0.f, a3 = 0.f;
#pragma unroll
    for (int q = 0; q < 16; ++q) {
        float4 e = e4[q];
        a0 = fmaf(xv[4*q+0], e.x, a0);
        a1 = fmaf(xv[4*q+1], e.y, a1);
        a2 = fmaf(xv[4*q+2], e.z, a2);
        a3 = fmaf(xv[4*q+3], e.w, a3);
    }
    return (a0 + a1) + (a2 + a3);
}

__global__ __launch_bounds__(256) void vq_out(const float* __restrict__ x,
                                              const float* __restrict__ ws,
                                              float* __restrict__ out,
                                              float* __restrict__ partial) {
    const float* ET = ws + WS_ET;
    const float* EN = ws + WS_EN;
    int n  = blockIdx.x * 256 + threadIdx.x;
    int b  = n >> 12;
    int hw = n & 4095;

    const float* xp = x + ((size_t)b << 18) + hw;
    float xv[D];
#pragma unroll
    for (int d = 0; d < D; ++d) xv[d] = xp[(size_t)d << 12];

    unsigned packed = ((const unsigned*)out)[I_OFF + n];
    int c1 = (int)(packed & 0xffffu), c2 = (int)(packed >> 16);

    float d1 = fmaf(-2.f, dotrow(ET + (c1 << 6), xv), EN[c1]);
    float d2 = fmaf(-2.f, dotrow(ET + (c2 << 6), xv), EN[c2]);
    bool sw = (d2 < d1) || (d2 == d1 && c2 < c1);   // np.argmin: first min wins
    int bestk = sw ? c2 : c1;

    out[I_OFF + n] = (float)bestk;

    const float* qv = ET + (bestk << 6);
    float* op = out + Q_OFF + ((size_t)b << 18) + hw;
    float lsum = 0.f;
#pragma unroll
    for (int d = 0; d < D; ++d) {
        float qd = qv[d];
        op[(size_t)d << 12] = qd;
        float diff = xv[d] - qd;
        lsum = fmaf(diff, diff, lsum);
    }

#pragma unroll
    for (int off = 32; off > 0; off >>= 1)
        lsum += __shfl_down(lsum, off, 64);
    __shared__ float wsum[4];
    if ((threadIdx.x & 63) == 0) wsum[threadIdx.x >> 6] = lsum;
    __syncthreads();
    if (threadIdx.x == 0)
        partial[blockIdx.x] = (wsum[0] + wsum[1]) + (wsum[2] + wsum[3]);
}

__global__ __launch_bounds__(256) void vq_final(const float* __restrict__ partial,
                                                float* __restrict__ out) {
    int t = threadIdx.x;
    float s = partial[t] + partial[t + 256];
#pragma unroll
    for (int off = 32; off > 0; off >>= 1)
        s += __shfl_down(s, off, 64);
    __shared__ float wsum[4];
    if ((t & 63) == 0) wsum[t >> 6] = s;
    __syncthreads();
    if (t == 0)
        out[L_OFF] = ((wsum[0] + wsum[1]) + (wsum[2] + wsum[3])) * (1.f / 8388608.f);
}

extern "C" void kernel_launch(void* const* d_in, const int* in_sizes, int n_in,
                              void* d_out, int out_size, void* d_ws, size_t ws_size,
                              hipStream_t stream) {
    const float* x = (const float*)d_in[0];
    const float* E = (const float*)d_in[1];
    float* out = (float*)d_out;
    float* ws  = (float*)d_ws;

    hipLaunchKernelGGL(vq_prep,  dim3(8),    dim3(256), 0, stream, E, ws, out);
    hipLaunchKernelGGL(vq_dist,  dim3(1024), dim3(256), 0, stream, x, ws, out);
    hipLaunchKernelGGL(vq_out,   dim3(512),  dim3(256), 0, stream, x, ws, out, ws + WS_PART);
    hipLaunchKernelGGL(vq_final, dim3(1),    dim3(256), 0, stream, ws + WS_PART, out);
}